// Round 2
// baseline (166.254 us; speedup 1.0000x reference)
//
#include <hip/hip_runtime.h>
#include <hip/hip_bf16.h>
#include <stdint.h>

#define NTOK 49
#define DIM  128
#define NH   4
#define QKVN 384
#define SCALE 0.17677669529663687f

typedef __bf16 bfloat_t;
typedef bfloat_t bf16x8 __attribute__((ext_vector_type(8)));
typedef bfloat_t bf16x4 __attribute__((ext_vector_type(4)));
typedef float f32x4 __attribute__((ext_vector_type(4)));

__device__ __forceinline__ bf16x8 cvt8(f32x4 lo, f32x4 hi) {
    bf16x8 r;
    r[0] = (bfloat_t)lo[0]; r[1] = (bfloat_t)lo[1]; r[2] = (bfloat_t)lo[2]; r[3] = (bfloat_t)lo[3];
    r[4] = (bfloat_t)hi[0]; r[5] = (bfloat_t)hi[1]; r[6] = (bfloat_t)hi[2]; r[7] = (bfloat_t)hi[3];
    return r;
}

__global__ void prep_weights(const float* __restrict__ qkvw,
                             const float* __restrict__ projw,
                             bfloat_t* __restrict__ qkvw_b,
                             bfloat_t* __restrict__ projw_b) {
    int i = blockIdx.x * 256 + threadIdx.x;
    if (i < QKVN * DIM) qkvw_b[i] = (bfloat_t)qkvw[i];
    if (i < DIM * DIM)  projw_b[i] = (bfloat_t)projw[i];
}

// cmb[w][h][tok_q(64)][tok_k(64)] = bias + mask; tok_k>=49 -> -1e30; tok_q>=49 -> 0
__global__ void prep_cmb(const float* __restrict__ mask,
                         const float* __restrict__ bias_table,
                         const int* __restrict__ rel_index,
                         float* __restrict__ cmb) {
    int wh = blockIdx.x;            // w*NH + h
    int w = wh >> 2, h = wh & 3;
    for (int idx = threadIdx.x; idx < 4096; idx += 256) {
        int row = idx >> 6, col = idx & 63;   // row=tok_q, col=tok_k
        float v;
        if (col >= NTOK)      v = -1e30f;
        else if (row >= NTOK) v = 0.f;
        else v = bias_table[rel_index[row * NTOK + col] * NH + h]
               + mask[(w * NTOK + row) * NTOK + col];
        cmb[(size_t)wh * 4096 + idx] = v;
    }
}

// LDS per-wave region (12288 B): q[64tok][32d] swz @0, k @4096, vT[32d][64tok] swz @8192.
// P[64tq][64tk] swz overlays q+k (8192 B). ao[64tok][128d] swz overlays waves 0-1 after barrier.
__global__ __launch_bounds__(256, 3)
void win_attn(const float* __restrict__ x,
              const float* __restrict__ qkv_b,
              const float* __restrict__ proj_b,
              const bfloat_t* __restrict__ qkvw,
              const bfloat_t* __restrict__ projw,
              const float* __restrict__ cmb,
              float* __restrict__ out, int nw) {
    __shared__ __align__(16) char smem[49152];
    const int b    = blockIdx.x;
    const int tid  = threadIdx.x;
    const int wave = tid >> 6;          // = head h
    const int lane = tid & 63;
    const int g = lane >> 4;
    const int c = lane & 15;
    const int h = wave;

    char* Wq = smem + wave * 12288;
    char* Wk = Wq + 4096;
    char* Wv = Wq + 8192;
    char* Pp = Wq;                      // overlays q+k after S is computed

    // ---- x fragments straight from global: xf[t16][ks] = x[t16*16+c][ks*32+g*8..+8] ----
    bf16x8 xf[4][4];
    {
        const float* xb = x + (size_t)b * (NTOK * DIM);
        #pragma unroll
        for (int t = 0; t < 4; ++t) {
            const int tok = t * 16 + c;
            const bool ok = (tok < NTOK);            // rows 49..63 -> 0 (avoid OOB)
            const float* rp = xb + tok * DIM;
            #pragma unroll
            for (int ks = 0; ks < 4; ++ks) {
                f32x4 lo = ok ? *(const f32x4*)(rp + ks * 32 + g * 8)     : (f32x4){0.f,0.f,0.f,0.f};
                f32x4 hi = ok ? *(const f32x4*)(rp + ks * 32 + g * 8 + 4) : (f32x4){0.f,0.f,0.f,0.f};
                xf[t][ks] = cvt8(lo, hi);
            }
        }
    }

    // ---- q^T = Wq_h · x^T : D[m=d(32)][n=tok(64)] ----
    {
        f32x4 acc[2][4];
        #pragma unroll
        for (int mtd = 0; mtd < 2; ++mtd) {
            const f32x4 qb4 = *(const f32x4*)(qkv_b + h * 32 + mtd * 16 + g * 4);
            #pragma unroll
            for (int nt = 0; nt < 4; ++nt) acc[mtd][nt] = qb4;
        }
        #pragma unroll
        for (int ks = 0; ks < 4; ++ks) {
            bf16x8 w0 = *(const bf16x8*)(qkvw + (h * 32 +  0 + c) * DIM + ks * 32 + g * 8);
            bf16x8 w1 = *(const bf16x8*)(qkvw + (h * 32 + 16 + c) * DIM + ks * 32 + g * 8);
            #pragma unroll
            for (int nt = 0; nt < 4; ++nt) {
                acc[0][nt] = __builtin_amdgcn_mfma_f32_16x16x32_bf16(w0, xf[nt][ks], acc[0][nt], 0, 0, 0);
                acc[1][nt] = __builtin_amdgcn_mfma_f32_16x16x32_bf16(w1, xf[nt][ks], acc[1][nt], 0, 0, 0);
            }
        }
        #pragma unroll
        for (int mtd = 0; mtd < 2; ++mtd)
            #pragma unroll
            for (int nt = 0; nt < 4; ++nt) {
                f32x4 a = acc[mtd][nt];
                bf16x4 pk = { (bfloat_t)(a[0]*SCALE), (bfloat_t)(a[1]*SCALE),
                              (bfloat_t)(a[2]*SCALE), (bfloat_t)(a[3]*SCALE) };
                // q[tok=nt*16+c][d0=mtd*16+g*4 ..+3], swz granule ^= tok&3
                const int byte = (nt*16 + c)*64 + (((2*mtd + (g>>1)) ^ (c&3)) << 4) + ((g&1) << 3);
                *(bf16x4*)(Wq + byte) = pk;
            }
    }

    // ---- k^T = Wk_h · x^T ----
    {
        f32x4 acc[2][4];
        #pragma unroll
        for (int mtd = 0; mtd < 2; ++mtd) {
            const f32x4 kb4 = *(const f32x4*)(qkv_b + DIM + h * 32 + mtd * 16 + g * 4);
            #pragma unroll
            for (int nt = 0; nt < 4; ++nt) acc[mtd][nt] = kb4;
        }
        #pragma unroll
        for (int ks = 0; ks < 4; ++ks) {
            bf16x8 w0 = *(const bf16x8*)(qkvw + (DIM + h * 32 +  0 + c) * DIM + ks * 32 + g * 8);
            bf16x8 w1 = *(const bf16x8*)(qkvw + (DIM + h * 32 + 16 + c) * DIM + ks * 32 + g * 8);
            #pragma unroll
            for (int nt = 0; nt < 4; ++nt) {
                acc[0][nt] = __builtin_amdgcn_mfma_f32_16x16x32_bf16(w0, xf[nt][ks], acc[0][nt], 0, 0, 0);
                acc[1][nt] = __builtin_amdgcn_mfma_f32_16x16x32_bf16(w1, xf[nt][ks], acc[1][nt], 0, 0, 0);
            }
        }
        #pragma unroll
        for (int mtd = 0; mtd < 2; ++mtd)
            #pragma unroll
            for (int nt = 0; nt < 4; ++nt) {
                f32x4 a = acc[mtd][nt];
                bf16x4 pk = { (bfloat_t)a[0], (bfloat_t)a[1], (bfloat_t)a[2], (bfloat_t)a[3] };
                const int byte = (nt*16 + c)*64 + (((2*mtd + (g>>1)) ^ (c&3)) << 4) + ((g&1) << 3);
                *(bf16x4*)(Wk + byte) = pk;
            }
    }

    // ---- v = x · Wv_h^T : D[m=tok][n=d] -> vT[d][tok] ----
    {
        f32x4 acc[4][2];
        #pragma unroll
        for (int nt = 0; nt < 2; ++nt) {
            const float vb = qkv_b[2 * DIM + h * 32 + nt * 16 + c];
            #pragma unroll
            for (int mt = 0; mt < 4; ++mt) acc[mt][nt] = (f32x4){vb, vb, vb, vb};
        }
        #pragma unroll
        for (int ks = 0; ks < 4; ++ks) {
            bf16x8 w0 = *(const bf16x8*)(qkvw + (2 * DIM + h * 32 +  0 + c) * DIM + ks * 32 + g * 8);
            bf16x8 w1 = *(const bf16x8*)(qkvw + (2 * DIM + h * 32 + 16 + c) * DIM + ks * 32 + g * 8);
            #pragma unroll
            for (int mt = 0; mt < 4; ++mt) {
                acc[mt][0] = __builtin_amdgcn_mfma_f32_16x16x32_bf16(xf[mt][ks], w0, acc[mt][0], 0, 0, 0);
                acc[mt][1] = __builtin_amdgcn_mfma_f32_16x16x32_bf16(xf[mt][ks], w1, acc[mt][1], 0, 0, 0);
            }
        }
        #pragma unroll
        for (int mt = 0; mt < 4; ++mt)
            #pragma unroll
            for (int nt = 0; nt < 2; ++nt) {
                f32x4 a = acc[mt][nt];
                bf16x4 pk = { (bfloat_t)a[0], (bfloat_t)a[1], (bfloat_t)a[2], (bfloat_t)a[3] };
                // vT[d=nt*16+c][tok0=mt*16+g*4 ..+3], swz granule ^= d&7
                const int byte = (nt*16 + c)*128 + (((2*mt + (g>>1)) ^ (c&7)) << 4) + ((g&1) << 3);
                *(bf16x4*)(Wv + byte) = pk;
            }
    }

    // ---- S^T = k · q^T with C-init = cmb^T; softmax along tok_k (mostly lane-local) ----
    float dinv[4];
    {
        const float* cw = cmb + (size_t)((b % nw) * NH + h) * 4096;
        f32x4 s[4][4];
        #pragma unroll
        for (int mtk = 0; mtk < 4; ++mtk)
            #pragma unroll
            for (int ntq = 0; ntq < 4; ++ntq)
                s[mtk][ntq] = *(const f32x4*)(cw + (ntq * 16 + c) * 64 + mtk * 16 + g * 4);
        bf16x8 kf[4], qf[4];
        #pragma unroll
        for (int t = 0; t < 4; ++t) {
            kf[t] = *(const bf16x8*)(Wk + (t*16 + c)*64 + ((g ^ (c&3)) << 4));
            qf[t] = *(const bf16x8*)(Wq + (t*16 + c)*64 + ((g ^ (c&3)) << 4));
        }
        #pragma unroll
        for (int mtk = 0; mtk < 4; ++mtk)
            #pragma unroll
            for (int ntq = 0; ntq < 4; ++ntq)
                s[mtk][ntq] = __builtin_amdgcn_mfma_f32_16x16x32_bf16(kf[mtk], qf[ntq], s[mtk][ntq], 0, 0, 0);

        #pragma unroll
        for (int ntq = 0; ntq < 4; ++ntq) {
            float m = s[0][ntq][0];
            #pragma unroll
            for (int mtk = 0; mtk < 4; ++mtk)
                #pragma unroll
                for (int r = 0; r < 4; ++r) m = fmaxf(m, s[mtk][ntq][r]);
            m = fmaxf(m, __shfl_xor(m, 16));
            m = fmaxf(m, __shfl_xor(m, 32));
            float sum = 0.f;
            #pragma unroll
            for (int mtk = 0; mtk < 4; ++mtk)
                #pragma unroll
                for (int r = 0; r < 4; ++r) {
                    float p = __expf(s[mtk][ntq][r] - m);
                    s[mtk][ntq][r] = p;
                    sum += p;
                }
            sum += __shfl_xor(sum, 16);
            sum += __shfl_xor(sum, 32);
            dinv[ntq] = 1.f / sum;
        }
        // P[tok_q][tok_k] (swz granule ^= tok_q&7), b64 writes of 4-consec tok_k
        #pragma unroll
        for (int mtk = 0; mtk < 4; ++mtk)
            #pragma unroll
            for (int ntq = 0; ntq < 4; ++ntq) {
                f32x4 a = s[mtk][ntq];
                bf16x4 pk = { (bfloat_t)a[0], (bfloat_t)a[1], (bfloat_t)a[2], (bfloat_t)a[3] };
                const int byte = (ntq*16 + c)*128 + (((2*mtk + (g>>1)) ^ (c&7)) << 4) + ((g&1) << 3);
                *(bf16x4*)(Pp + byte) = pk;
            }
    }

    // ---- O^T = vT · P^T : D[m=d(32)][n=tok_q(64)], then scale cols by dinv ----
    {
        f32x4 o[2][4];
        #pragma unroll
        for (int mtd = 0; mtd < 2; ++mtd)
            #pragma unroll
            for (int ntq = 0; ntq < 4; ++ntq) o[mtd][ntq] = (f32x4){0.f,0.f,0.f,0.f};
        #pragma unroll
        for (int ks = 0; ks < 2; ++ks) {
            bf16x8 vf[2], pf[4];
            #pragma unroll
            for (int mtd = 0; mtd < 2; ++mtd)
                vf[mtd] = *(const bf16x8*)(Wv + (mtd*16 + c)*128 + (((ks*4 + g) ^ (c&7)) << 4));
            #pragma unroll
            for (int ntq = 0; ntq < 4; ++ntq)
                pf[ntq] = *(const bf16x8*)(Pp + (ntq*16 + c)*128 + (((ks*4 + g) ^ (c&7)) << 4));
            #pragma unroll
            for (int mtd = 0; mtd < 2; ++mtd)
                #pragma unroll
                for (int ntq = 0; ntq < 4; ++ntq)
                    o[mtd][ntq] = __builtin_amdgcn_mfma_f32_16x16x32_bf16(vf[mtd], pf[ntq], o[mtd][ntq], 0, 0, 0);
        }
        #pragma unroll
        for (int mtd = 0; mtd < 2; ++mtd)
            #pragma unroll
            for (int ntq = 0; ntq < 4; ++ntq)
                #pragma unroll
                for (int r = 0; r < 4; ++r) o[mtd][ntq][r] *= dinv[ntq];

        __syncthreads();   // everyone done reading vT/P before ao overlays wave regions
        // ao[tok][d] (swz granule ^= tok&15): write 4-consec d at fixed tok
        #pragma unroll
        for (int mtd = 0; mtd < 2; ++mtd)
            #pragma unroll
            for (int ntq = 0; ntq < 4; ++ntq) {
                f32x4 a = o[mtd][ntq];
                bf16x4 pk = { (bfloat_t)a[0], (bfloat_t)a[1], (bfloat_t)a[2], (bfloat_t)a[3] };
                const int byte = (ntq*16 + c)*256 + ((((h*4 + 2*mtd + (g>>1)) ^ c) & 15) << 4) + ((g&1) << 3);
                *(bf16x4*)(smem + byte) = pk;
            }
    }
    __syncthreads();

    // ---- out^T = Wp · ao^T : D[m=outcol(32/wave)][n=tok(64)]; f32x4 global stores ----
    {
        f32x4 po[2][4];
        #pragma unroll
        for (int mtO = 0; mtO < 2; ++mtO) {
            const f32x4 pb4 = *(const f32x4*)(proj_b + wave * 32 + mtO * 16 + g * 4);
            #pragma unroll
            for (int nt = 0; nt < 4; ++nt) po[mtO][nt] = pb4;
        }
        #pragma unroll
        for (int ks = 0; ks < 4; ++ks) {
            bf16x8 w0 = *(const bf16x8*)(projw + (wave * 32 +  0 + c) * DIM + ks * 32 + g * 8);
            bf16x8 w1 = *(const bf16x8*)(projw + (wave * 32 + 16 + c) * DIM + ks * 32 + g * 8);
            bf16x8 aof[4];
            #pragma unroll
            for (int nt = 0; nt < 4; ++nt)
                aof[nt] = *(const bf16x8*)(smem + (nt*16 + c)*256 + ((((ks*4 + g) ^ c) & 15) << 4));
            #pragma unroll
            for (int nt = 0; nt < 4; ++nt) {
                po[0][nt] = __builtin_amdgcn_mfma_f32_16x16x32_bf16(w0, aof[nt], po[0][nt], 0, 0, 0);
                po[1][nt] = __builtin_amdgcn_mfma_f32_16x16x32_bf16(w1, aof[nt], po[1][nt], 0, 0, 0);
            }
        }
        float* og = out + (size_t)b * (NTOK * DIM);
        #pragma unroll
        for (int nt = 0; nt < 4; ++nt) {
            const int tok = nt * 16 + c;
            if (tok < NTOK) {
                #pragma unroll
                for (int mtO = 0; mtO < 2; ++mtO)
                    *(f32x4*)(og + tok * DIM + wave * 32 + mtO * 16 + g * 4) = po[mtO][nt];
            }
        }
    }
}

extern "C" void kernel_launch(void* const* d_in, const int* in_sizes, int n_in,
                              void* d_out, int out_size, void* d_ws, size_t ws_size,
                              hipStream_t stream) {
    (void)n_in; (void)out_size; (void)ws_size;
    const float* x          = (const float*)d_in[0];
    const float* mask       = (const float*)d_in[1];
    const float* qkv_w      = (const float*)d_in[2];
    const float* qkv_b      = (const float*)d_in[3];
    const float* proj_w     = (const float*)d_in[4];
    const float* proj_b     = (const float*)d_in[5];
    const float* bias_table = (const float*)d_in[6];
    const int*   rel_index  = (const int*)d_in[7];
    float* out = (float*)d_out;

    char* ws = (char*)d_ws;
    bfloat_t* qkvw_b  = (bfloat_t*)ws;              // 98304 B
    bfloat_t* projw_b = (bfloat_t*)(ws + 98304);    // 32768 B
    float*    cmb     = (float*)(ws + 131072);      // nw*NH*64*64*4 B

    const int B  = in_sizes[0] / (NTOK * DIM);
    const int nw = in_sizes[1] / (NTOK * NTOK);

    prep_weights<<<dim3((QKVN * DIM + 255) / 256), dim3(256), 0, stream>>>(qkv_w, proj_w, qkvw_b, projw_b);
    prep_cmb<<<dim3(nw * NH), dim3(256), 0, stream>>>(mask, bias_table, rel_index, cmb);
    win_attn<<<dim3(B), dim3(256), 0, stream>>>(x, qkv_b, proj_b, qkvw_b, projw_b, cmb, out, nw);
}